// Round 3
// baseline (5109.037 us; speedup 1.0000x reference)
//
#include <hip/hip_runtime.h>
#include <math.h>

#define DD 12
#define D2 144
#define D3 1728
#define D4 20736
#define SLB 1872   // 144 * 13 padded slab

typedef float2 c32;

__device__ __forceinline__ c32 cmul(c32 a, c32 b) {
  return make_float2(a.x * b.x - a.y * b.y, a.x * b.y + a.y * b.x);
}
__device__ __forceinline__ c32 cfma(c32 a, c32 b, c32 acc) {
  acc.x = fmaf(a.x, b.x, fmaf(-a.y, b.y, acc.x));
  acc.y = fmaf(a.x, b.y, fmaf(a.y, b.x, acc.y));
  return acc;
}
#define CZERO make_float2(0.f, 0.f)

// sector offsets: secoff[N] = sum_{n<N} sz(n)^2 (+sentinel)
__constant__ int d_secoff[24] = {0,1,5,14,30,55,91,140,204,285,385,506,650,
                                 771,871,952,1016,1065,1101,1126,1142,1151,1155,1156};
// cumulative R=2 task counts per sector (ceil(sz/2)), 78 total
__constant__ int d_CP[24] = {0,1,2,4,6,9,12,16,20,25,30,36,42,
                             48,53,58,62,66,69,72,74,76,77,78};

struct BsTask {
  int sz, goff, a23, s23, a12, s12, w23, w12;
  bool act, v1;
};

__device__ __forceinline__ BsTask bs_task(int tau) {
  int N = 0;
#pragma unroll
  for (int q = 1; q < 24; ++q) N = (tau >= d_CP[q]) ? q : N;
  BsTask T;
  T.act = (tau < 78);
  N = (N > 22) ? 22 : N;
  const int k = tau - d_CP[N];
  const bool up = (N <= 11);
  const int lo = up ? 0 : (N - 11);
  T.sz = up ? (N + 1) : (23 - N);
  const int i0 = lo + 2 * k;
  T.v1 = T.act && (2 * k + 1 < T.sz);
  T.goff = d_secoff[N] + 2 * k * T.sz;
  T.a23 = up ? N : (132 + N);    // 12*i' + N at p=0 (downs iterate i' descending)
  T.s23 = up ? 12 : -12;
  T.a12 = up ? N : (121 + N);    // row q_in = 11*i' + M at p=0
  T.s12 = up ? 11 : -11;
  T.w23 = 12 * i0 + N;           // write base (per-spectator-block c32 index)
  T.w12 = 13 * (11 * i0 + N);    // write base (c32 index)
  return T;
}

// BS pass, spectator = leading mode (stride 156 c32), pattern = trailing 2 modes
__device__ __forceinline__ void pass_bs23(const c32* cur, c32* nxt, const c32* gate, const BsTask& T) {
  if (!T.act) return;
  c32 acc0[12], acc1[12];
#pragma unroll
  for (int n = 0; n < 12; ++n) { acc0[n] = CZERO; acc1[n] = CZERO; }
#pragma unroll
  for (int p = 0; p < 12; ++p) {
    const bool mp = (p < T.sz);
    c32 g0 = gate[T.goff + p];
    c32 g1 = gate[T.goff + T.sz + p];
    if (!mp) g0 = CZERO;
    if (!(mp && T.v1)) g1 = CZERO;
    const c32* pa = cur + (T.a23 + T.s23 * p);
#pragma unroll
    for (int n = 0; n < 12; ++n) {
      c32 v = pa[156 * n];
      acc0[n] = cfma(g0, v, acc0[n]);
      acc1[n] = cfma(g1, v, acc1[n]);
    }
  }
  c32* pw = nxt + T.w23;
#pragma unroll
  for (int n = 0; n < 12; ++n) pw[156 * n] = acc0[n];
  if (T.v1) {
#pragma unroll
    for (int n = 0; n < 12; ++n) pw[156 * n + 12] = acc1[n];
  }
}

// BS pass, pattern = leading 2 modes (rows), spectator = trailing mode (in-row)
__device__ __forceinline__ void pass_bsrow(const c32* cur, c32* nxt, const c32* gate, const BsTask& T) {
  if (!T.act) return;
  c32 acc0[12], acc1[12];
#pragma unroll
  for (int n = 0; n < 12; ++n) { acc0[n] = CZERO; acc1[n] = CZERO; }
#pragma unroll
  for (int p = 0; p < 12; ++p) {
    const bool mp = (p < T.sz);
    c32 g0 = gate[T.goff + p];
    c32 g1 = gate[T.goff + T.sz + p];
    if (!mp) g0 = CZERO;
    if (!(mp && T.v1)) g1 = CZERO;
    const c32* pa = cur + 13 * (T.a12 + T.s12 * p);
#pragma unroll
    for (int n = 0; n < 12; ++n) {
      c32 v = pa[n];
      acc0[n] = cfma(g0, v, acc0[n]);
      acc1[n] = cfma(g1, v, acc1[n]);
    }
  }
  c32* pw = nxt + T.w12;
#pragma unroll
  for (int n = 0; n < 12; ++n) pw[n] = acc0[n];
  if (T.v1) {
#pragma unroll
    for (int n = 0; n < 12; ++n) pw[143 + n] = acc1[n];
  }
}

// 1-mode gate on leading mode of a (mode, nn)-row pair: reads rows j*12+nn
__device__ __forceinline__ void pass_uA(const c32* cur, c32* nxt, const c32* gv, int tau) {
  if (tau >= 72) return;
  const int ip = tau / 12, nn = tau - ip * 12;
  c32 acc0[12], acc1[12];
#pragma unroll
  for (int n = 0; n < 12; ++n) { acc0[n] = CZERO; acc1[n] = CZERO; }
#pragma unroll
  for (int j = 0; j < 12; ++j) {
    c32 ga = gv[(2 * ip) * 12 + j];
    c32 gb = gv[(2 * ip + 1) * 12 + j];
    const c32* pa = cur + 156 * j + 13 * nn;
#pragma unroll
    for (int n = 0; n < 12; ++n) {
      c32 v = pa[n];
      acc0[n] = cfma(ga, v, acc0[n]);
      acc1[n] = cfma(gb, v, acc1[n]);
    }
  }
  c32* pw = nxt + 13 * (24 * ip + nn);
#pragma unroll
  for (int n = 0; n < 12; ++n) { pw[n] = acc0[n]; pw[156 + n] = acc1[n]; }
}

// 1-mode gate on middle mode: reads rows n1*12+j
__device__ __forceinline__ void pass_uB(const c32* cur, c32* nxt, const c32* gv, int tau) {
  if (tau >= 72) return;
  const int ip = tau / 12, n1 = tau - ip * 12;
  c32 acc0[12], acc1[12];
#pragma unroll
  for (int n = 0; n < 12; ++n) { acc0[n] = CZERO; acc1[n] = CZERO; }
#pragma unroll
  for (int j = 0; j < 12; ++j) {
    c32 ga = gv[(2 * ip) * 12 + j];
    c32 gb = gv[(2 * ip + 1) * 12 + j];
    const c32* pa = cur + 156 * n1 + 13 * j;
#pragma unroll
    for (int n = 0; n < 12; ++n) {
      c32 v = pa[n];
      acc0[n] = cfma(ga, v, acc0[n]);
      acc1[n] = cfma(gb, v, acc1[n]);
    }
  }
  c32* pw = nxt + 13 * (12 * n1 + 2 * ip);
#pragma unroll
  for (int n = 0; n < 12; ++n) { pw[n] = acc0[n]; pw[13 + n] = acc1[n]; }
}

// 1-mode gate on trailing mode: rows self-contained
__device__ __forceinline__ void pass_uC(const c32* cur, c32* nxt, const c32* gv, int tau) {
  if (tau >= 72) return;
  const int q0 = 2 * tau;
  c32 w0[12], w1[12];
  const c32* pa = cur + 13 * q0;
#pragma unroll
  for (int k = 0; k < 12; ++k) { w0[k] = pa[k]; w1[k] = pa[13 + k]; }
  c32* pw = nxt + 13 * q0;
#pragma unroll
  for (int i = 0; i < 12; ++i) {
    c32 s0 = CZERO, s1 = CZERO;
#pragma unroll
    for (int j = 0; j < 12; ++j) {
      c32 g = gv[i * 12 + j];
      s0 = cfma(g, w0[j], s0);
      s1 = cfma(g, w1[j], s1);
    }
    pw[i] = s0;
    pw[13 + i] = s1;
  }
}

// ---------------- small matrix expm (LDS, 64-thread block) ----------------
__device__ void small_expm(c32* A, c32* S, c32* P, c32* T, float* red, int sz, int tid) {
  const int n2 = sz * sz;
  if (tid < sz) {
    float s = 0.f;
    for (int j = 0; j < sz; ++j) { c32 v = A[tid * sz + j]; s += sqrtf(fmaf(v.x, v.x, v.y * v.y)); }
    red[tid] = s;
  }
  __syncthreads();
  float nrm = 0.f;
  for (int i = 0; i < sz; ++i) nrm = fmaxf(nrm, red[i]);
  int sp = 0;
  while (nrm > 0.35f && sp < 24) { nrm *= 0.5f; ++sp; }
  const float scale = ldexpf(1.f, -sp);
  for (int e = tid; e < n2; e += 64) { A[e].x *= scale; A[e].y *= scale; }
  __syncthreads();
  for (int e = tid; e < n2; e += 64) {
    c32 a = A[e];
    P[e] = a;
    if ((e / sz) == (e % sz)) a.x += 1.f;
    S[e] = a;
  }
  __syncthreads();
  for (int k = 2; k <= 12; ++k) {
    const float inv = 1.f / (float)k;
    for (int e = tid; e < n2; e += 64) {
      int i = e / sz, j = e - i * sz;
      c32 acc = CZERO;
      for (int q = 0; q < sz; ++q) acc = cfma(P[i * sz + q], A[q * sz + j], acc);
      acc.x *= inv; acc.y *= inv;
      T[e] = acc;
    }
    __syncthreads();
    for (int e = tid; e < n2; e += 64) {
      c32 t = T[e];
      P[e] = t;
      S[e].x += t.x; S[e].y += t.y;
    }
    __syncthreads();
  }
  for (int q = 0; q < sp; ++q) {
    for (int e = tid; e < n2; e += 64) {
      int i = e / sz, j = e - i * sz;
      c32 acc = CZERO;
      for (int w = 0; w < sz; ++w) acc = cfma(S[i * sz + w], S[w * sz + j], acc);
      T[e] = acc;
    }
    __syncthreads();
    for (int e = tid; e < n2; e += 64) S[e] = T[e];
    __syncthreads();
  }
}

// ---------------- prep: per-batch displacement encoding (store col 0) ----------------
__global__ __launch_bounds__(64) void prep_disp(const float* __restrict__ x, c32* __restrict__ c0) {
  __shared__ c32 A[144], S[144], P[144], T[144];
  __shared__ float red[12];
  const int tid = threadIdx.x;
  const int b = blockIdx.x >> 2, m = blockIdx.x & 3;
  const float rr = x[b * 8 + m], ph = x[b * 8 + 4 + m];
  float sn, cs;
  sincosf(ph, &sn, &cs);
  const c32 alpha = make_float2(rr * cs, rr * sn);
  for (int e = tid; e < 144; e += 64) A[e] = CZERO;
  __syncthreads();
  if (tid < 11) {
    float sq = sqrtf((float)(tid + 1));
    A[(tid + 1) * 12 + tid] = make_float2(alpha.x * sq, alpha.y * sq);
    A[tid * 12 + tid + 1] = make_float2(-alpha.x * sq, alpha.y * sq);
  }
  __syncthreads();
  small_expm(A, S, P, T, red, 12, tid);
  if (tid < 12) c0[(size_t)blockIdx.x * 12 + tid] = S[tid * 12];
}

// ---------------- prep: beamsplitter sector blocks (direction-arranged) ----------------
__global__ __launch_bounds__(64) void prep_bs(const float* __restrict__ th1, const float* __restrict__ ph1,
                                              const float* __restrict__ th2, const float* __restrict__ ph2,
                                              c32* __restrict__ BS) {
  __shared__ c32 A[144], S[144], P[144], T[144];
  __shared__ float red[12];
  const int tid = threadIdx.x;
  const int g = blockIdx.x / 23, N = blockIdx.x % 23;
  const int l = g / 12, rem = g % 12, w = rem / 6, gi = rem % 6;
  const float th = (w ? th2 : th1)[l * 6 + gi];
  const float ph = (w ? ph2 : ph1)[l * 6 + gi];
  const int lo = (N > 11) ? (N - 11) : 0;
  const int sz = (N <= 11) ? (N + 1) : (23 - N);
  float sn, cs;
  sincosf(ph, &sn, &cs);
  for (int e = tid; e < sz * sz; e += 64) A[e] = CZERO;
  __syncthreads();
  if (tid + 1 < sz) {
    int t = tid + 1;
    float s1 = th * sqrtf((float)((lo + t) * (N - lo - t + 1)));
    A[(t - 1) * sz + t] = make_float2(cs * s1, sn * s1);
    A[t * sz + t - 1] = make_float2(-cs * s1, sn * s1);
  }
  __syncthreads();
  small_expm(A, S, P, T, red, sz, tid);
  c32* dst = BS + (size_t)g * 1156 + d_secoff[N];
  const bool upSec = (N <= 11);
  for (int e = tid; e < sz * sz; e += 64) {
    int p = e / sz, q = e - p * sz;
    int qs = upSec ? q : (sz - 1 - q);
    dst[p * sz + q] = S[p * sz + qs];
  }
}

// ---------------- prep: per-mode composites P1 = S*R1, P2 = K*Disp*R2 ----------------
__global__ __launch_bounds__(64) void prep_p(const float* __restrict__ r_, const float* __restrict__ phir,
                                             const float* __restrict__ vphi1,
                                             const float* __restrict__ a_, const float* __restrict__ phia,
                                             const float* __restrict__ vphi2, const float* __restrict__ kk,
                                             c32* __restrict__ P1, c32* __restrict__ P2) {
  __shared__ c32 A[144], S[144], P[144], T[144];
  __shared__ float red[12];
  const int tid = threadIdx.x;
  const int which = blockIdx.x >> 3, lm = blockIdx.x & 7;
  for (int e = tid; e < 144; e += 64) A[e] = CZERO;
  __syncthreads();
  if (which == 0) {
    const float rv = r_[lm], pv = phir[lm];
    float sn, cs;
    sincosf(pv, &sn, &cs);
    const c32 z = make_float2(rv * cs, rv * sn);
    if (tid < 10) {
      float sq = 0.5f * sqrtf((float)((tid + 1) * (tid + 2)));
      A[tid * 12 + tid + 2] = make_float2(z.x * sq, -z.y * sq);
      A[(tid + 2) * 12 + tid] = make_float2(-z.x * sq, -z.y * sq);
    }
  } else {
    const float av = a_[lm], pv = phia[lm];
    float sn, cs;
    sincosf(pv, &sn, &cs);
    const c32 alpha = make_float2(av * cs, av * sn);
    if (tid < 11) {
      float sq = sqrtf((float)(tid + 1));
      A[(tid + 1) * 12 + tid] = make_float2(alpha.x * sq, alpha.y * sq);
      A[tid * 12 + tid + 1] = make_float2(-alpha.x * sq, alpha.y * sq);
    }
  }
  __syncthreads();
  small_expm(A, S, P, T, red, 12, tid);
  if (which == 0) {
    const float vp = vphi1[lm];
    for (int e = tid; e < 144; e += 64) {
      int j = e % 12;
      float sn, cs;
      sincosf(vp * (float)j, &sn, &cs);
      P1[(size_t)lm * 144 + e] = cmul(S[e], make_float2(cs, sn));
    }
  } else {
    const float vp = vphi2[lm], kv = kk[lm];
    for (int e = tid; e < 144; e += 64) {
      int i = e / 12, j = e % 12;
      float sn1, cs1, sn2, cs2;
      sincosf(vp * (float)j, &sn1, &cs1);
      float ang = kv * (float)i;
      ang *= (float)i;
      sincosf(ang, &sn2, &cs2);
      P2[(size_t)lm * 144 + e] = cmul(make_float2(cs2, sn2), cmul(S[e], make_float2(cs1, sn1)));
    }
  }
}

// ---------------- fused pass over modes {1,2,3}: BS(2,3) -> BS(1,2) -> U1 -> U2 -> U3 ----------------
// 2 slabs per 256-thread block, [144][13]-padded LDS, R=2 row-paired tasks.
__global__ __launch_bounds__(256) void k123_kernel(
    c32* __restrict__ psi,
    const c32* __restrict__ gbs23, const c32* __restrict__ gbs12,
    const c32* __restrict__ gu1, const c32* __restrict__ gu2, const c32* __restrict__ gu3) {
  __shared__ c32 buf[2][2][SLB];
  __shared__ c32 gate[1168];
  __shared__ c32 gV[3][144];
  const int tid = threadIdx.x;
  if (gu1) for (int e = tid; e < 144; e += 256) gV[0][e] = gu1[e];
  if (gu2) for (int e = tid; e < 144; e += 256) gV[1][e] = gu2[e];
  if (gu3) for (int e = tid; e < 144; e += 256) gV[2][e] = gu3[e];
  for (int e = tid; e < 1156; e += 256) gate[e] = gbs23[e];
  c32* gsl = psi + (size_t)blockIdx.x * (2 * D3);
  for (int f = tid; f < 1728; f += 256) {
    int s = (f >= 864), ff = f - 864 * s;
    int row = ff / 6, pr = ff - row * 6;
    float4 v = ((const float4*)gsl)[f];
    int la = row * 13 + pr * 2;
    buf[s][0][la] = make_float2(v.x, v.y);
    buf[s][0][la + 1] = make_float2(v.z, v.w);
  }
  __syncthreads();
  const int s = tid >> 7, tau = tid & 127;
  const BsTask T = bs_task(tau);
  pass_bs23(buf[s][0], buf[s][1], gate, T);
  __syncthreads();
  for (int e = tid; e < 1156; e += 256) gate[e] = gbs12[e];
  __syncthreads();
  pass_bsrow(buf[s][1], buf[s][0], gate, T);
  int c = 0;
  if (gu1) { __syncthreads(); pass_uA(buf[s][c], buf[s][c ^ 1], gV[0], tau); c ^= 1; }
  if (gu2) { __syncthreads(); pass_uB(buf[s][c], buf[s][c ^ 1], gV[1], tau); c ^= 1; }
  if (gu3) { __syncthreads(); pass_uC(buf[s][c], buf[s][c ^ 1], gV[2], tau); c ^= 1; }
  __syncthreads();
  for (int f = tid; f < 1728; f += 256) {
    int s2 = (f >= 864), ff = f - 864 * s2;
    int row = ff / 6, pr = ff - row * 6;
    const c32* sb = buf[s2][c];
    c32 a = sb[row * 13 + pr * 2], d = sb[row * 13 + pr * 2 + 1];
    ((float4*)gsl)[f] = make_float4(a.x, a.y, d.x, d.y);
  }
}

// ---------------- fused pass over modes {0,1}: [init] -> U0 -> BS(0,1) ----------------
// 2 tiles (= n2 values) per block; tile = 144 (n0,n1)-rows x 12 n3-cols, [144][13] LDS.
__global__ __launch_bounds__(256) void k01_kernel(
    c32* __restrict__ psi, const c32* __restrict__ c0,
    const c32* __restrict__ gu0, const c32* __restrict__ gbs) {
  __shared__ c32 buf[2][2][SLB];
  __shared__ c32 gate[1168];
  __shared__ c32 g0v[144];
  __shared__ c32 cv[4][12];
  const int tid = threadIdx.x;
  const int b = blockIdx.x / 6, tp = blockIdx.x % 6;
  if (gu0) for (int e = tid; e < 144; e += 256) g0v[e] = gu0[e];
  if (gbs) for (int e = tid; e < 1156; e += 256) gate[e] = gbs[e];
  c32* gb = psi + (size_t)b * D4;
  if (c0) {
    if (tid < 48) cv[tid / 12][tid % 12] = c0[(size_t)b * 48 + tid];
    __syncthreads();
    for (int e = tid; e < 3456; e += 256) {
      int s = (e >= 1728), ee = e - 1728 * s;
      int row = ee / 12, cc = ee - row * 12;
      c32 val = cmul(cmul(cv[0][row / 12], cv[1][row % 12]), cmul(cv[2][2 * tp + s], cv[3][cc]));
      buf[s][0][row * 13 + cc] = val;
    }
  } else {
    for (int f = tid; f < 1728; f += 256) {
      int s = (f >= 864), ff = f - 864 * s;
      int row = ff / 6, pr = ff - row * 6;
      int t = 2 * tp + s;
      float4 v = *(const float4*)(gb + (size_t)row * 144 + t * 12 + pr * 2);
      int la = row * 13 + pr * 2;
      buf[s][0][la] = make_float2(v.x, v.y);
      buf[s][0][la + 1] = make_float2(v.z, v.w);
    }
  }
  __syncthreads();
  const int s = tid >> 7, tau = tid & 127;
  int c = 0;
  if (gu0) {
    pass_uA(buf[s][0], buf[s][1], g0v, tau);
    c = 1;
    __syncthreads();
  }
  if (gbs) {
    const BsTask T = bs_task(tau);
    pass_bsrow(buf[s][c], buf[s][c ^ 1], gate, T);
    c ^= 1;
    __syncthreads();
  }
  for (int f = tid; f < 1728; f += 256) {
    int s2 = (f >= 864), ff = f - 864 * s2;
    int row = ff / 6, pr = ff - row * 6;
    int t = 2 * tp + s2;
    const c32* sb = buf[s2][c];
    c32 a = sb[row * 13 + pr * 2], d = sb[row * 13 + pr * 2 + 1];
    *(float4*)(gb + (size_t)row * 144 + t * 12 + pr * 2) = make_float4(a.x, a.y, d.x, d.y);
  }
}

// ---------------- expvals: <X_m> = sum 2*sqrt(n+1)*Re(conj(psi_n) psi_{n+1}) ----------------
__global__ __launch_bounds__(256) void expval_kernel(const c32* __restrict__ psi, float* __restrict__ out) {
  __shared__ float red[1024];
  __shared__ float sq2[12];
  const int tid = threadIdx.x, b = blockIdx.x;
  if (tid < 12) sq2[tid] = 2.f * sqrtf((float)(tid + 1));
  __syncthreads();
  const c32* base = psi + (size_t)b * D4;
  float a0 = 0.f, a1 = 0.f, a2 = 0.f, a3 = 0.f;
  for (int e = tid; e < D4; e += 256) {
    c32 p = base[e];
    int n3 = e % 12, t = e / 12;
    int n2 = t % 12; t /= 12;
    int n1 = t % 12, n0 = t / 12;
    if (n3 < 11) { c32 q = base[e + 1];    a3 = fmaf(sq2[n3], fmaf(p.x, q.x, p.y * q.y), a3); }
    if (n2 < 11) { c32 q = base[e + 12];   a2 = fmaf(sq2[n2], fmaf(p.x, q.x, p.y * q.y), a2); }
    if (n1 < 11) { c32 q = base[e + 144];  a1 = fmaf(sq2[n1], fmaf(p.x, q.x, p.y * q.y), a1); }
    if (n0 < 11) { c32 q = base[e + 1728]; a0 = fmaf(sq2[n0], fmaf(p.x, q.x, p.y * q.y), a0); }
  }
  red[tid * 4 + 0] = a0; red[tid * 4 + 1] = a1; red[tid * 4 + 2] = a2; red[tid * 4 + 3] = a3;
  __syncthreads();
  for (int sdown = 128; sdown > 0; sdown >>= 1) {
    if (tid < sdown) {
      red[tid * 4 + 0] += red[(tid + sdown) * 4 + 0];
      red[tid * 4 + 1] += red[(tid + sdown) * 4 + 1];
      red[tid * 4 + 2] += red[(tid + sdown) * 4 + 2];
      red[tid * 4 + 3] += red[(tid + sdown) * 4 + 3];
    }
    __syncthreads();
  }
  if (tid < 4) out[b * 4 + tid] = red[tid];
}

extern "C" void kernel_launch(void* const* d_in, const int* in_sizes, int n_in,
                              void* d_out, int out_size, void* d_ws, size_t ws_size,
                              hipStream_t stream) {
  const float* x      = (const float*)d_in[0];
  const float* theta1 = (const float*)d_in[1];
  const float* phi1   = (const float*)d_in[2];
  const float* vphi1  = (const float*)d_in[3];
  const float* r_     = (const float*)d_in[4];
  const float* phir   = (const float*)d_in[5];
  const float* theta2 = (const float*)d_in[6];
  const float* phi2   = (const float*)d_in[7];
  const float* vphi2  = (const float*)d_in[8];
  const float* a_     = (const float*)d_in[9];
  const float* phia   = (const float*)d_in[10];
  const float* kk     = (const float*)d_in[11];
  float* out = (float*)d_out;

  // workspace layout (bytes)
  const size_t PSI_OFF = 0;                              // 1024*20736*8
  const size_t C0_OFF  = 169869312;                      // 1024*4*12*8
  const size_t P1_OFF  = C0_OFF + 393216;
  const size_t P2_OFF  = P1_OFF + 9216;
  const size_t BS_OFF  = P2_OFF + 9216;                  // 24*1156*8
  const size_t NEED    = BS_OFF + 221952;
  if (ws_size < NEED) return;

  char* ws = (char*)d_ws;
  c32* psi = (c32*)(ws + PSI_OFF);
  c32* c0  = (c32*)(ws + C0_OFF);
  c32* P1  = (c32*)(ws + P1_OFF);
  c32* P2  = (c32*)(ws + P2_OFF);
  c32* BS  = (c32*)(ws + BS_OFF);

  prep_disp<<<dim3(4096), dim3(64), 0, stream>>>(x, c0);
  prep_bs<<<dim3(552), dim3(64), 0, stream>>>(theta1, phi1, theta2, phi2, BS);
  prep_p<<<dim3(16), dim3(64), 0, stream>>>(r_, phir, vphi1, a_, phia, vphi2, kk, P1, P2);

  for (int l = 0; l < 2; ++l) {
    c32* bsl = BS + (size_t)l * 12 * 1156;
    const c32* c0arg = (l == 0) ? c0 : (const c32*)nullptr;
    const c32* u0pre = (l == 0) ? (const c32*)nullptr : (const c32*)(P2 + (size_t)(l - 1) * 4 * 144);
    // interferometer 1: Clements order (0,1),(2,3),(1,2),(0,1),(2,3),(1,2)
    k01_kernel<<<dim3(6144), dim3(256), 0, stream>>>(psi, c0arg, u0pre, bsl + 0 * 1156);
    k123_kernel<<<dim3(6144), dim3(256), 0, stream>>>(psi, bsl + 1 * 1156, bsl + 2 * 1156,
                                                      nullptr, nullptr, nullptr);
    k01_kernel<<<dim3(6144), dim3(256), 0, stream>>>(psi, nullptr, nullptr, bsl + 3 * 1156);
    k123_kernel<<<dim3(6144), dim3(256), 0, stream>>>(psi, bsl + 4 * 1156, bsl + 5 * 1156,
                                                      P1 + (size_t)(l * 4 + 1) * 144,
                                                      P1 + (size_t)(l * 4 + 2) * 144,
                                                      P1 + (size_t)(l * 4 + 3) * 144);
    // interferometer 2 (P1 mode-0 composite rides along before its first BS(0,1))
    k01_kernel<<<dim3(6144), dim3(256), 0, stream>>>(psi, nullptr, P1 + (size_t)(l * 4 + 0) * 144, bsl + 6 * 1156);
    k123_kernel<<<dim3(6144), dim3(256), 0, stream>>>(psi, bsl + 7 * 1156, bsl + 8 * 1156,
                                                      nullptr, nullptr, nullptr);
    k01_kernel<<<dim3(6144), dim3(256), 0, stream>>>(psi, nullptr, nullptr, bsl + 9 * 1156);
    k123_kernel<<<dim3(6144), dim3(256), 0, stream>>>(psi, bsl + 10 * 1156, bsl + 11 * 1156,
                                                      P2 + (size_t)(l * 4 + 1) * 144,
                                                      P2 + (size_t)(l * 4 + 2) * 144,
                                                      P2 + (size_t)(l * 4 + 3) * 144);
  }
  // final pending mode-0 composite from layer 2
  k01_kernel<<<dim3(6144), dim3(256), 0, stream>>>(psi, nullptr, P2 + (size_t)(1 * 4 + 0) * 144, nullptr);
  expval_kernel<<<dim3(1024), dim3(256), 0, stream>>>(psi, out);
}

// Round 4
// 4447.563 us; speedup vs baseline: 1.1487x; 1.1487x over previous
//
#include <hip/hip_runtime.h>
#include <math.h>

#define D4 20736

typedef float2 c32;

__device__ __forceinline__ c32 cmul(c32 a, c32 b) {
  return make_float2(a.x * b.x - a.y * b.y, a.x * b.y + a.y * b.x);
}
__device__ __forceinline__ c32 cfma(c32 a, c32 b, c32 acc) {
  acc.x = fmaf(a.x, b.x, fmaf(-a.y, b.y, acc.x));
  acc.y = fmaf(a.x, b.y, fmaf(a.y, b.x, acc.y));
  return acc;
}
__device__ __forceinline__ float4 pack2(c32 a, c32 b) {
  return make_float4(a.x, a.y, b.x, b.y);
}
#define CZERO make_float2(0.f, 0.f)

// swizzled [144][16] c32 layout: row stride 16 c32 (128 B); 8 float4-chunks per
// row; physical chunk = chunk ^ (row & 7)  -> conflict-free-ish for both
// row-gather and column-gather access.
__device__ __forceinline__ int lx(int row, int n) {
  return row * 16 + (((((n >> 1) ^ (row & 7)) << 1)) | (n & 1));
}
__device__ __forceinline__ int lx4(int row, int c) {
  return row * 16 + ((c ^ (row & 7)) << 1);
}

// sector offsets: secoff[N] = sum_{n<N} sz(n)^2 (+sentinel)
__constant__ int d_secoff[24] = {0,1,5,14,30,55,91,140,204,285,385,506,650,
                                 771,871,952,1016,1065,1101,1126,1142,1151,1155,1156};
// cumulative R=2 pair counts per sector (ceil(sz/2)), 78 total
__constant__ int d_CP[24] = {0,1,2,4,6,9,12,16,20,25,30,36,42,
                             48,53,58,62,66,69,72,74,76,77,78};

struct BsT {
  int sz, goff, N, i0, rA, sA, p20, ps;
  bool act, v1;
};

__device__ __forceinline__ BsT bs_pair(int pr) {
  BsT T;
  T.act = (pr < 78);
  int N = 0;
#pragma unroll
  for (int q = 1; q <= 23; ++q) N = (pr >= d_CP[q]) ? q : N;
  if (!T.act) { T.sz = 1; T.goff = 0; T.N = 0; T.i0 = 0; T.rA = 0; T.sA = 0;
                T.p20 = 0; T.ps = 0; T.v1 = false; return T; }
  const int k = pr - d_CP[N];
  const bool up = (N <= 11);
  const int lo = up ? 0 : (N - 11);
  T.sz = up ? (N + 1) : (23 - N);
  T.i0 = lo + 2 * k;
  T.v1 = (2 * k + 1 < T.sz);
  T.goff = d_secoff[N] + 2 * k * T.sz;
  T.N = N;
  T.rA = up ? N : (121 + N);   // input pattern-row 11*p2+N at q=0
  T.sA = up ? 11 : -11;
  T.p20 = up ? 0 : 11;         // p2 walk for crossing gather
  T.ps = up ? 1 : -1;
  return T;
}

// BS where the sector pattern lives on the ROWS (i,j)->row=12i+j, spectator is
// 6 contiguous in-row cols (half h).
__device__ __forceinline__ void pass_bsrow(const c32* cur, c32* nxt, const c32* gate,
                                           const BsT& T, int h) {
  if (!T.act) return;
  c32 acc0[6], acc1[6];
#pragma unroll
  for (int n = 0; n < 6; ++n) { acc0[n] = CZERO; acc1[n] = CZERO; }
  int row = T.rA;
#pragma unroll
  for (int q = 0; q < 12; ++q) {
    const bool mq = (q < T.sz);
    c32 g0 = gate[T.goff + q];
    c32 g1 = gate[T.goff + T.sz + q];
    if (!mq) g0 = CZERO;
    if (!(mq && T.v1)) g1 = CZERO;
    float4 w0 = *(const float4*)(cur + lx4(row, 3 * h + 0));
    float4 w1 = *(const float4*)(cur + lx4(row, 3 * h + 1));
    float4 w2 = *(const float4*)(cur + lx4(row, 3 * h + 2));
    c32 v[6] = {{w0.x,w0.y},{w0.z,w0.w},{w1.x,w1.y},{w1.z,w1.w},{w2.x,w2.y},{w2.z,w2.w}};
#pragma unroll
    for (int n = 0; n < 6; ++n) {
      acc0[n] = cfma(g0, v[n], acc0[n]);
      acc1[n] = cfma(g1, v[n], acc1[n]);
    }
    row += T.sA;
  }
  const int r0 = 11 * T.i0 + T.N;
  *(float4*)(nxt + lx4(r0, 3 * h + 0)) = pack2(acc0[0], acc0[1]);
  *(float4*)(nxt + lx4(r0, 3 * h + 1)) = pack2(acc0[2], acc0[3]);
  *(float4*)(nxt + lx4(r0, 3 * h + 2)) = pack2(acc0[4], acc0[5]);
  if (T.v1) {
    const int r1 = r0 + 11;
    *(float4*)(nxt + lx4(r1, 3 * h + 0)) = pack2(acc1[0], acc1[1]);
    *(float4*)(nxt + lx4(r1, 3 * h + 1)) = pack2(acc1[2], acc1[3]);
    *(float4*)(nxt + lx4(r1, 3 * h + 2)) = pack2(acc1[4], acc1[5]);
  }
}

// BS where the pattern crosses row-low-part (p2) and the col (p3): element
// (n1,p2,p3) at row 12*n1+p2, col p3. Spectator n1 in 6-half h.
__device__ __forceinline__ void pass_cross(const c32* cur, c32* nxt, const c32* gate,
                                           const BsT& T, int h) {
  if (!T.act) return;
  c32 acc0[6], acc1[6];
#pragma unroll
  for (int n = 0; n < 6; ++n) { acc0[n] = CZERO; acc1[n] = CZERO; }
  int p2 = T.p20;
#pragma unroll
  for (int q = 0; q < 12; ++q) {
    const bool mq = (q < T.sz);
    c32 g0 = gate[T.goff + q];
    c32 g1 = gate[T.goff + T.sz + q];
    if (!mq) g0 = CZERO;
    if (!(mq && T.v1)) g1 = CZERO;
    const int p3 = (T.N - p2) & 15;  // clamp masked iterations in-row
#pragma unroll
    for (int n = 0; n < 6; ++n) {
      c32 v = cur[lx(12 * (6 * h + n) + p2, p3)];
      acc0[n] = cfma(g0, v, acc0[n]);
      acc1[n] = cfma(g1, v, acc1[n]);
    }
    p2 += T.ps;
  }
  const int i2 = T.i0, j2 = T.N - T.i0;
#pragma unroll
  for (int n = 0; n < 6; ++n) nxt[lx(12 * (6 * h + n) + i2, j2)] = acc0[n];
  if (T.v1) {
#pragma unroll
    for (int n = 0; n < 6; ++n) nxt[lx(12 * (6 * h + n) + i2 + 1, j2 - 1)] = acc1[n];
  }
}

// 1-mode gate on the LEADING row-mode: reads rows j*12+nn. tau=(ip,nn,h).
__device__ __forceinline__ void pass_uA(const c32* cur, c32* nxt, const c32* gv, int tau) {
  if (tau >= 144) return;
  const int ip = tau / 24, rem = tau % 24, nn = rem >> 1, h = rem & 1;
  c32 acc0[6], acc1[6];
#pragma unroll
  for (int n = 0; n < 6; ++n) { acc0[n] = CZERO; acc1[n] = CZERO; }
#pragma unroll
  for (int j = 0; j < 12; ++j) {
    const int row = j * 12 + nn;
    c32 ga = gv[(2 * ip) * 12 + j];
    c32 gb = gv[(2 * ip + 1) * 12 + j];
    float4 w0 = *(const float4*)(cur + lx4(row, 3 * h + 0));
    float4 w1 = *(const float4*)(cur + lx4(row, 3 * h + 1));
    float4 w2 = *(const float4*)(cur + lx4(row, 3 * h + 2));
    c32 v[6] = {{w0.x,w0.y},{w0.z,w0.w},{w1.x,w1.y},{w1.z,w1.w},{w2.x,w2.y},{w2.z,w2.w}};
#pragma unroll
    for (int n = 0; n < 6; ++n) {
      acc0[n] = cfma(ga, v[n], acc0[n]);
      acc1[n] = cfma(gb, v[n], acc1[n]);
    }
  }
  const int r0 = (2 * ip) * 12 + nn, r1 = r0 + 12;
  *(float4*)(nxt + lx4(r0, 3 * h + 0)) = pack2(acc0[0], acc0[1]);
  *(float4*)(nxt + lx4(r0, 3 * h + 1)) = pack2(acc0[2], acc0[3]);
  *(float4*)(nxt + lx4(r0, 3 * h + 2)) = pack2(acc0[4], acc0[5]);
  *(float4*)(nxt + lx4(r1, 3 * h + 0)) = pack2(acc1[0], acc1[1]);
  *(float4*)(nxt + lx4(r1, 3 * h + 1)) = pack2(acc1[2], acc1[3]);
  *(float4*)(nxt + lx4(r1, 3 * h + 2)) = pack2(acc1[4], acc1[5]);
}

// 1-mode gate on the TRAILING row-mode: reads rows n1*12+j. tau=(n1,ip,h).
__device__ __forceinline__ void pass_uB(const c32* cur, c32* nxt, const c32* gv, int tau) {
  if (tau >= 144) return;
  const int n1 = tau / 12, rem = tau % 12, ip = rem >> 1, h = rem & 1;
  c32 acc0[6], acc1[6];
#pragma unroll
  for (int n = 0; n < 6; ++n) { acc0[n] = CZERO; acc1[n] = CZERO; }
#pragma unroll
  for (int j = 0; j < 12; ++j) {
    const int row = n1 * 12 + j;
    c32 ga = gv[(2 * ip) * 12 + j];
    c32 gb = gv[(2 * ip + 1) * 12 + j];
    float4 w0 = *(const float4*)(cur + lx4(row, 3 * h + 0));
    float4 w1 = *(const float4*)(cur + lx4(row, 3 * h + 1));
    float4 w2 = *(const float4*)(cur + lx4(row, 3 * h + 2));
    c32 v[6] = {{w0.x,w0.y},{w0.z,w0.w},{w1.x,w1.y},{w1.z,w1.w},{w2.x,w2.y},{w2.z,w2.w}};
#pragma unroll
    for (int n = 0; n < 6; ++n) {
      acc0[n] = cfma(ga, v[n], acc0[n]);
      acc1[n] = cfma(gb, v[n], acc1[n]);
    }
  }
  const int r0 = n1 * 12 + 2 * ip, r1 = r0 + 1;
  *(float4*)(nxt + lx4(r0, 3 * h + 0)) = pack2(acc0[0], acc0[1]);
  *(float4*)(nxt + lx4(r0, 3 * h + 1)) = pack2(acc0[2], acc0[3]);
  *(float4*)(nxt + lx4(r0, 3 * h + 2)) = pack2(acc0[4], acc0[5]);
  *(float4*)(nxt + lx4(r1, 3 * h + 0)) = pack2(acc1[0], acc1[1]);
  *(float4*)(nxt + lx4(r1, 3 * h + 1)) = pack2(acc1[2], acc1[3]);
  *(float4*)(nxt + lx4(r1, 3 * h + 2)) = pack2(acc1[4], acc1[5]);
}

// 1-mode gate on the COLUMN mode: each task owns one full row.
__device__ __forceinline__ void pass_uC(const c32* cur, c32* nxt, const c32* gv, int tau) {
  if (tau >= 144) return;
  const int r = tau;
  c32 w[12];
#pragma unroll
  for (int c = 0; c < 6; ++c) {
    float4 q = *(const float4*)(cur + lx4(r, c));
    w[2 * c] = make_float2(q.x, q.y);
    w[2 * c + 1] = make_float2(q.z, q.w);
  }
#pragma unroll
  for (int c = 0; c < 6; ++c) {
    c32 s0 = CZERO, s1 = CZERO;
#pragma unroll
    for (int j = 0; j < 12; ++j) {
      s0 = cfma(gv[(2 * c) * 12 + j], w[j], s0);
      s1 = cfma(gv[(2 * c + 1) * 12 + j], w[j], s1);
    }
    *(float4*)(nxt + lx4(r, c)) = pack2(s0, s1);
  }
}

// ---------------- small matrix expm (LDS, 64-thread block) ----------------
__device__ void small_expm(c32* A, c32* S, c32* P, c32* T, float* red, int sz, int tid) {
  const int n2 = sz * sz;
  if (tid < sz) {
    float s = 0.f;
    for (int j = 0; j < sz; ++j) { c32 v = A[tid * sz + j]; s += sqrtf(fmaf(v.x, v.x, v.y * v.y)); }
    red[tid] = s;
  }
  __syncthreads();
  float nrm = 0.f;
  for (int i = 0; i < sz; ++i) nrm = fmaxf(nrm, red[i]);
  int sp = 0;
  while (nrm > 0.35f && sp < 24) { nrm *= 0.5f; ++sp; }
  const float scale = ldexpf(1.f, -sp);
  for (int e = tid; e < n2; e += 64) { A[e].x *= scale; A[e].y *= scale; }
  __syncthreads();
  for (int e = tid; e < n2; e += 64) {
    c32 a = A[e];
    P[e] = a;
    if ((e / sz) == (e % sz)) a.x += 1.f;
    S[e] = a;
  }
  __syncthreads();
  for (int k = 2; k <= 12; ++k) {
    const float inv = 1.f / (float)k;
    for (int e = tid; e < n2; e += 64) {
      int i = e / sz, j = e - i * sz;
      c32 acc = CZERO;
      for (int q = 0; q < sz; ++q) acc = cfma(P[i * sz + q], A[q * sz + j], acc);
      acc.x *= inv; acc.y *= inv;
      T[e] = acc;
    }
    __syncthreads();
    for (int e = tid; e < n2; e += 64) {
      c32 t = T[e];
      P[e] = t;
      S[e].x += t.x; S[e].y += t.y;
    }
    __syncthreads();
  }
  for (int q = 0; q < sp; ++q) {
    for (int e = tid; e < n2; e += 64) {
      int i = e / sz, j = e - i * sz;
      c32 acc = CZERO;
      for (int w = 0; w < sz; ++w) acc = cfma(S[i * sz + w], S[w * sz + j], acc);
      T[e] = acc;
    }
    __syncthreads();
    for (int e = tid; e < n2; e += 64) S[e] = T[e];
    __syncthreads();
  }
}

// ---------------- prep: per-batch displacement encoding (store col 0) ----------------
__global__ __launch_bounds__(64) void prep_disp(const float* __restrict__ x, c32* __restrict__ c0) {
  __shared__ c32 A[144], S[144], P[144], T[144];
  __shared__ float red[12];
  const int tid = threadIdx.x;
  const int b = blockIdx.x >> 2, m = blockIdx.x & 3;
  const float rr = x[b * 8 + m], ph = x[b * 8 + 4 + m];
  float sn, cs;
  sincosf(ph, &sn, &cs);
  const c32 alpha = make_float2(rr * cs, rr * sn);
  for (int e = tid; e < 144; e += 64) A[e] = CZERO;
  __syncthreads();
  if (tid < 11) {
    float sq = sqrtf((float)(tid + 1));
    A[(tid + 1) * 12 + tid] = make_float2(alpha.x * sq, alpha.y * sq);
    A[tid * 12 + tid + 1] = make_float2(-alpha.x * sq, alpha.y * sq);
  }
  __syncthreads();
  small_expm(A, S, P, T, red, 12, tid);
  if (tid < 12) c0[(size_t)blockIdx.x * 12 + tid] = S[tid * 12];
}

// ---------------- prep: beamsplitter sector blocks (direction-arranged) ----------------
__global__ __launch_bounds__(64) void prep_bs(const float* __restrict__ th1, const float* __restrict__ ph1,
                                              const float* __restrict__ th2, const float* __restrict__ ph2,
                                              c32* __restrict__ BS) {
  __shared__ c32 A[144], S[144], P[144], T[144];
  __shared__ float red[12];
  const int tid = threadIdx.x;
  const int g = blockIdx.x / 23, N = blockIdx.x % 23;
  const int l = g / 12, rem = g % 12, w = rem / 6, gi = rem % 6;
  const float th = (w ? th2 : th1)[l * 6 + gi];
  const float ph = (w ? ph2 : ph1)[l * 6 + gi];
  const int lo = (N > 11) ? (N - 11) : 0;
  const int sz = (N <= 11) ? (N + 1) : (23 - N);
  float sn, cs;
  sincosf(ph, &sn, &cs);
  for (int e = tid; e < sz * sz; e += 64) A[e] = CZERO;
  __syncthreads();
  if (tid + 1 < sz) {
    int t = tid + 1;
    float s1 = th * sqrtf((float)((lo + t) * (N - lo - t + 1)));
    A[(t - 1) * sz + t] = make_float2(cs * s1, sn * s1);
    A[t * sz + t - 1] = make_float2(-cs * s1, sn * s1);
  }
  __syncthreads();
  small_expm(A, S, P, T, red, sz, tid);
  c32* dst = BS + (size_t)g * 1156 + d_secoff[N];
  const bool upSec = (N <= 11);
  for (int e = tid; e < sz * sz; e += 64) {
    int p = e / sz, q = e - p * sz;
    int qs = upSec ? q : (sz - 1 - q);
    dst[p * sz + q] = S[p * sz + qs];
  }
}

// ---------------- prep: per-mode composites P1 = S*R1, P2 = K*Disp*R2 ----------------
__global__ __launch_bounds__(64) void prep_p(const float* __restrict__ r_, const float* __restrict__ phir,
                                             const float* __restrict__ vphi1,
                                             const float* __restrict__ a_, const float* __restrict__ phia,
                                             const float* __restrict__ vphi2, const float* __restrict__ kk,
                                             c32* __restrict__ P1, c32* __restrict__ P2) {
  __shared__ c32 A[144], S[144], P[144], T[144];
  __shared__ float red[12];
  const int tid = threadIdx.x;
  const int which = blockIdx.x >> 3, lm = blockIdx.x & 7;
  for (int e = tid; e < 144; e += 64) A[e] = CZERO;
  __syncthreads();
  if (which == 0) {
    const float rv = r_[lm], pv = phir[lm];
    float sn, cs;
    sincosf(pv, &sn, &cs);
    const c32 z = make_float2(rv * cs, rv * sn);
    if (tid < 10) {
      float sq = 0.5f * sqrtf((float)((tid + 1) * (tid + 2)));
      A[tid * 12 + tid + 2] = make_float2(z.x * sq, -z.y * sq);
      A[(tid + 2) * 12 + tid] = make_float2(-z.x * sq, -z.y * sq);
    }
  } else {
    const float av = a_[lm], pv = phia[lm];
    float sn, cs;
    sincosf(pv, &sn, &cs);
    const c32 alpha = make_float2(av * cs, av * sn);
    if (tid < 11) {
      float sq = sqrtf((float)(tid + 1));
      A[(tid + 1) * 12 + tid] = make_float2(alpha.x * sq, alpha.y * sq);
      A[tid * 12 + tid + 1] = make_float2(-alpha.x * sq, alpha.y * sq);
    }
  }
  __syncthreads();
  small_expm(A, S, P, T, red, 12, tid);
  if (which == 0) {
    const float vp = vphi1[lm];
    for (int e = tid; e < 144; e += 64) {
      int j = e % 12;
      float sn, cs;
      sincosf(vp * (float)j, &sn, &cs);
      P1[(size_t)lm * 144 + e] = cmul(S[e], make_float2(cs, sn));
    }
  } else {
    const float vp = vphi2[lm], kv = kk[lm];
    for (int e = tid; e < 144; e += 64) {
      int i = e / 12, j = e % 12;
      float sn1, cs1, sn2, cs2;
      sincosf(vp * (float)j, &sn1, &cs1);
      float ang = kv * (float)i;
      ang *= (float)i;
      sincosf(ang, &sn2, &cs2);
      P2[(size_t)lm * 144 + e] = cmul(make_float2(cs2, sn2), cmul(S[e], make_float2(cs1, sn1)));
    }
  }
}

// ---------------- fused pass over modes {1,2,3}: BS(2,3) -> BS(1,2) -> U1 -> U2 -> U3 ----------------
// Slab = (b, n0): rows (n1,n2), cols n3. One slab per 256-thread block.
__global__ __launch_bounds__(256, 3) void k123_kernel(
    c32* __restrict__ psi,
    const c32* __restrict__ gbs23, const c32* __restrict__ gbs12,
    const c32* __restrict__ gu1, const c32* __restrict__ gu2, const c32* __restrict__ gu3) {
  __shared__ __align__(16) c32 buf[2][2304];
  __shared__ c32 gate[1168];
  __shared__ c32 gV[3][144];
  const int tid = threadIdx.x;
  if (gu1) for (int e = tid; e < 144; e += 256) gV[0][e] = gu1[e];
  if (gu2) for (int e = tid; e < 144; e += 256) gV[1][e] = gu2[e];
  if (gu3) for (int e = tid; e < 144; e += 256) gV[2][e] = gu3[e];
  for (int e = tid; e < 1156; e += 256) gate[e] = gbs23[e];
  c32* slab = psi + (size_t)blockIdx.x * 1728;
  for (int f = tid; f < 864; f += 256) {
    float4 v = ((const float4*)slab)[f];
    *(float4*)(&buf[0][lx4(f / 6, f % 6)]) = v;
  }
  __syncthreads();
  const BsT T = bs_pair(tid >> 1);
  const int h = tid & 1;
  pass_cross(buf[0], buf[1], gate, T, h);   // BS(2,3)
  __syncthreads();
  for (int e = tid; e < 1156; e += 256) gate[e] = gbs12[e];
  __syncthreads();
  pass_bsrow(buf[1], buf[0], gate, T, h);   // BS(1,2)
  int c = 0;
  if (gu1) { __syncthreads(); pass_uA(buf[c], buf[c ^ 1], gV[0], tid); c ^= 1; }
  if (gu2) { __syncthreads(); pass_uB(buf[c], buf[c ^ 1], gV[1], tid); c ^= 1; }
  if (gu3) { __syncthreads(); pass_uC(buf[c], buf[c ^ 1], gV[2], tid); c ^= 1; }
  __syncthreads();
  for (int f = tid; f < 864; f += 256) {
    ((float4*)slab)[f] = *(const float4*)(&buf[c][lx4(f / 6, f % 6)]);
  }
}

// ---------------- fused pass over modes {0,1}: [init] -> U0 -> BS(0,1) ----------------
// Tile = (b, n2): rows (n0,n1), cols n3.
__global__ __launch_bounds__(256, 3) void k01_kernel(
    c32* __restrict__ psi, const c32* __restrict__ c0,
    const c32* __restrict__ gu0, const c32* __restrict__ gbs) {
  __shared__ __align__(16) c32 buf[2][2304];
  __shared__ c32 gate[1168];
  __shared__ c32 g0v[144];
  __shared__ c32 cv[4][12];
  const int tid = threadIdx.x;
  const int b = blockIdx.x / 12, t = blockIdx.x % 12;
  if (gu0) for (int e = tid; e < 144; e += 256) g0v[e] = gu0[e];
  if (gbs) for (int e = tid; e < 1156; e += 256) gate[e] = gbs[e];
  c32* gb = psi + (size_t)b * D4 + t * 12;
  if (c0) {
    if (tid < 48) cv[tid / 12][tid % 12] = c0[(size_t)b * 48 + tid];
    __syncthreads();
    for (int e = tid; e < 1728; e += 256) {
      int row = e / 12, n3 = e % 12;
      buf[0][lx(row, n3)] =
          cmul(cmul(cv[0][row / 12], cv[1][row % 12]), cmul(cv[2][t], cv[3][n3]));
    }
  } else {
    for (int f = tid; f < 864; f += 256) {
      int row = f / 6, cc = f % 6;
      float4 v = *(const float4*)(gb + (size_t)row * 144 + 2 * cc);
      *(float4*)(&buf[0][lx4(row, cc)]) = v;
    }
  }
  __syncthreads();
  const BsT T = bs_pair(tid >> 1);
  const int h = tid & 1;
  int c = 0;
  if (gu0) {
    pass_uA(buf[0], buf[1], g0v, tid);
    c = 1;
    __syncthreads();
  }
  if (gbs) {
    pass_bsrow(buf[c], buf[c ^ 1], gate, T, h);
    c ^= 1;
    __syncthreads();
  }
  for (int f = tid; f < 864; f += 256) {
    int row = f / 6, cc = f % 6;
    *(float4*)(gb + (size_t)row * 144 + 2 * cc) = *(const float4*)(&buf[c][lx4(row, cc)]);
  }
}

// ---------------- expvals: <X_m> = sum 2*sqrt(n+1)*Re(conj(psi_n) psi_{n+1}) ----------------
__global__ __launch_bounds__(256) void expval_kernel(const c32* __restrict__ psi, float* __restrict__ out) {
  __shared__ float red[1024];
  __shared__ float sq2[12];
  const int tid = threadIdx.x, b = blockIdx.x;
  if (tid < 12) sq2[tid] = 2.f * sqrtf((float)(tid + 1));
  __syncthreads();
  const c32* base = psi + (size_t)b * D4;
  float a0 = 0.f, a1 = 0.f, a2 = 0.f, a3 = 0.f;
  for (int e = tid; e < D4; e += 256) {
    c32 p = base[e];
    int n3 = e % 12, t = e / 12;
    int n2 = t % 12; t /= 12;
    int n1 = t % 12, n0 = t / 12;
    if (n3 < 11) { c32 q = base[e + 1];    a3 = fmaf(sq2[n3], fmaf(p.x, q.x, p.y * q.y), a3); }
    if (n2 < 11) { c32 q = base[e + 12];   a2 = fmaf(sq2[n2], fmaf(p.x, q.x, p.y * q.y), a2); }
    if (n1 < 11) { c32 q = base[e + 144];  a1 = fmaf(sq2[n1], fmaf(p.x, q.x, p.y * q.y), a1); }
    if (n0 < 11) { c32 q = base[e + 1728]; a0 = fmaf(sq2[n0], fmaf(p.x, q.x, p.y * q.y), a0); }
  }
  red[tid * 4 + 0] = a0; red[tid * 4 + 1] = a1; red[tid * 4 + 2] = a2; red[tid * 4 + 3] = a3;
  __syncthreads();
  for (int s = 128; s > 0; s >>= 1) {
    if (tid < s) {
      red[tid * 4 + 0] += red[(tid + s) * 4 + 0];
      red[tid * 4 + 1] += red[(tid + s) * 4 + 1];
      red[tid * 4 + 2] += red[(tid + s) * 4 + 2];
      red[tid * 4 + 3] += red[(tid + s) * 4 + 3];
    }
    __syncthreads();
  }
  if (tid < 4) out[b * 4 + tid] = red[tid];
}

extern "C" void kernel_launch(void* const* d_in, const int* in_sizes, int n_in,
                              void* d_out, int out_size, void* d_ws, size_t ws_size,
                              hipStream_t stream) {
  const float* x      = (const float*)d_in[0];
  const float* theta1 = (const float*)d_in[1];
  const float* phi1   = (const float*)d_in[2];
  const float* vphi1  = (const float*)d_in[3];
  const float* r_     = (const float*)d_in[4];
  const float* phir   = (const float*)d_in[5];
  const float* theta2 = (const float*)d_in[6];
  const float* phi2   = (const float*)d_in[7];
  const float* vphi2  = (const float*)d_in[8];
  const float* a_     = (const float*)d_in[9];
  const float* phia   = (const float*)d_in[10];
  const float* kk     = (const float*)d_in[11];
  float* out = (float*)d_out;

  // workspace layout (bytes)
  const size_t PSI_OFF = 0;                              // 1024*20736*8
  const size_t C0_OFF  = 169869312;                      // 1024*4*12*8
  const size_t P1_OFF  = C0_OFF + 393216;
  const size_t P2_OFF  = P1_OFF + 9216;
  const size_t BS_OFF  = P2_OFF + 9216;                  // 24*1156*8
  const size_t NEED    = BS_OFF + 221952;
  if (ws_size < NEED) return;

  char* ws = (char*)d_ws;
  c32* psi = (c32*)(ws + PSI_OFF);
  c32* c0  = (c32*)(ws + C0_OFF);
  c32* P1  = (c32*)(ws + P1_OFF);
  c32* P2  = (c32*)(ws + P2_OFF);
  c32* BS  = (c32*)(ws + BS_OFF);

  prep_disp<<<dim3(4096), dim3(64), 0, stream>>>(x, c0);
  prep_bs<<<dim3(552), dim3(64), 0, stream>>>(theta1, phi1, theta2, phi2, BS);
  prep_p<<<dim3(16), dim3(64), 0, stream>>>(r_, phir, vphi1, a_, phia, vphi2, kk, P1, P2);

  for (int l = 0; l < 2; ++l) {
    c32* bsl = BS + (size_t)l * 12 * 1156;
    const c32* c0arg = (l == 0) ? c0 : (const c32*)nullptr;
    const c32* u0pre = (l == 0) ? (const c32*)nullptr : (const c32*)(P2 + (size_t)(l - 1) * 4 * 144);
    // interferometer 1: Clements order (0,1),(2,3),(1,2),(0,1),(2,3),(1,2)
    k01_kernel<<<dim3(12288), dim3(256), 0, stream>>>(psi, c0arg, u0pre, bsl + 0 * 1156);
    k123_kernel<<<dim3(12288), dim3(256), 0, stream>>>(psi, bsl + 1 * 1156, bsl + 2 * 1156,
                                                       nullptr, nullptr, nullptr);
    k01_kernel<<<dim3(12288), dim3(256), 0, stream>>>(psi, nullptr, nullptr, bsl + 3 * 1156);
    k123_kernel<<<dim3(12288), dim3(256), 0, stream>>>(psi, bsl + 4 * 1156, bsl + 5 * 1156,
                                                       P1 + (size_t)(l * 4 + 1) * 144,
                                                       P1 + (size_t)(l * 4 + 2) * 144,
                                                       P1 + (size_t)(l * 4 + 3) * 144);
    // interferometer 2 (P1 mode-0 composite rides along before its first BS(0,1))
    k01_kernel<<<dim3(12288), dim3(256), 0, stream>>>(psi, nullptr, P1 + (size_t)(l * 4 + 0) * 144, bsl + 6 * 1156);
    k123_kernel<<<dim3(12288), dim3(256), 0, stream>>>(psi, bsl + 7 * 1156, bsl + 8 * 1156,
                                                       nullptr, nullptr, nullptr);
    k01_kernel<<<dim3(12288), dim3(256), 0, stream>>>(psi, nullptr, nullptr, bsl + 9 * 1156);
    k123_kernel<<<dim3(12288), dim3(256), 0, stream>>>(psi, bsl + 10 * 1156, bsl + 11 * 1156,
                                                       P2 + (size_t)(l * 4 + 1) * 144,
                                                       P2 + (size_t)(l * 4 + 2) * 144,
                                                       P2 + (size_t)(l * 4 + 3) * 144);
  }
  // final pending mode-0 composite from layer 2
  k01_kernel<<<dim3(12288), dim3(256), 0, stream>>>(psi, nullptr, P2 + (size_t)(1 * 4 + 0) * 144, nullptr);
  expval_kernel<<<dim3(1024), dim3(256), 0, stream>>>(psi, out);
}

// Round 5
// 2543.483 us; speedup vs baseline: 2.0087x; 1.7486x over previous
//
#include <hip/hip_runtime.h>
#include <math.h>

#define D4 20736
#define ST 14    // c32 row stride in k123 LDS (112B -> bank period 8, 16B aligned)
#define SST 168  // 12*ST: spectator stride for bs23
#define KP 18    // c32 row stride in k01 LDS (144B -> bank period 8)

typedef float2 c32;

__device__ __forceinline__ c32 cmul(c32 a, c32 b) {
  return make_float2(a.x * b.x - a.y * b.y, a.x * b.y + a.y * b.x);
}
__device__ __forceinline__ c32 cfma(c32 a, c32 b, c32 acc) {
  acc.x = fmaf(a.x, b.x, fmaf(-a.y, b.y, acc.x));
  acc.y = fmaf(a.x, b.y, fmaf(a.y, b.x, acc.y));
  return acc;
}
__device__ __forceinline__ c32 get2(const float4* w, int n) {
  float4 q = w[n >> 1];
  return (n & 1) ? make_float2(q.z, q.w) : make_float2(q.x, q.y);
}
__device__ __forceinline__ float4 pack2(c32 a, c32 b) {
  return make_float4(a.x, a.y, b.x, b.y);
}
#define CZERO make_float2(0.f, 0.f)

// sector offsets: secoff[N] = sum_{n<N} sz(n)^2
__constant__ int d_secoff[24] = {0,1,5,14,30,55,91,140,204,285,385,506,650,
                                 771,871,952,1016,1065,1101,1126,1142,1151,1155,1156};

struct RM { int goff, sz, a0, da, r0, dr; };
// metadata for output pattern-row r=(i,j); a-walk in 14-stride flat units (bs23),
// r-walk in row units (bs12/k01-bs). Down-sectors iterate descending (gates
// stored column-reversed by prep_bs).
__device__ __forceinline__ RM rmeta(int r) {
  const int i = r / 12, j = r - 12 * i, N = i + j;
  const bool up = (N <= 11);
  RM m;
  m.sz = (up ? N : 22 - N) + 1;
  const int lo = up ? 0 : (N - 11);
  m.goff = d_secoff[N] + (i - lo) * m.sz;
  m.a0 = up ? N : (143 + N);
  m.da = up ? 13 : -13;
  m.r0 = up ? N : (121 + N);
  m.dr = up ? 11 : -11;
  return m;
}

// ---------------- small matrix expm (LDS, 64-thread block) ----------------
__device__ void small_expm(c32* A, c32* S, c32* P, c32* T, float* red, int sz, int tid) {
  const int n2 = sz * sz;
  if (tid < sz) {
    float s = 0.f;
    for (int j = 0; j < sz; ++j) { c32 v = A[tid * sz + j]; s += sqrtf(fmaf(v.x, v.x, v.y * v.y)); }
    red[tid] = s;
  }
  __syncthreads();
  float nrm = 0.f;
  for (int i = 0; i < sz; ++i) nrm = fmaxf(nrm, red[i]);
  int sp = 0;
  while (nrm > 0.35f && sp < 24) { nrm *= 0.5f; ++sp; }
  const float scale = ldexpf(1.f, -sp);
  for (int e = tid; e < n2; e += 64) { A[e].x *= scale; A[e].y *= scale; }
  __syncthreads();
  for (int e = tid; e < n2; e += 64) {
    c32 a = A[e];
    P[e] = a;
    if ((e / sz) == (e % sz)) a.x += 1.f;
    S[e] = a;
  }
  __syncthreads();
  for (int k = 2; k <= 12; ++k) {
    const float inv = 1.f / (float)k;
    for (int e = tid; e < n2; e += 64) {
      int i = e / sz, j = e - i * sz;
      c32 acc = CZERO;
      for (int q = 0; q < sz; ++q) acc = cfma(P[i * sz + q], A[q * sz + j], acc);
      acc.x *= inv; acc.y *= inv;
      T[e] = acc;
    }
    __syncthreads();
    for (int e = tid; e < n2; e += 64) {
      c32 t = T[e];
      P[e] = t;
      S[e].x += t.x; S[e].y += t.y;
    }
    __syncthreads();
  }
  for (int q = 0; q < sp; ++q) {
    for (int e = tid; e < n2; e += 64) {
      int i = e / sz, j = e - i * sz;
      c32 acc = CZERO;
      for (int w = 0; w < sz; ++w) acc = cfma(S[i * sz + w], S[w * sz + j], acc);
      T[e] = acc;
    }
    __syncthreads();
    for (int e = tid; e < n2; e += 64) S[e] = T[e];
    __syncthreads();
  }
}

// ---------------- prep: per-batch displacement encoding (store col 0) ----------------
__global__ __launch_bounds__(64) void prep_disp(const float* __restrict__ x, c32* __restrict__ c0) {
  __shared__ c32 A[144], S[144], P[144], T[144];
  __shared__ float red[12];
  const int tid = threadIdx.x;
  const int b = blockIdx.x >> 2, m = blockIdx.x & 3;
  const float rr = x[b * 8 + m], ph = x[b * 8 + 4 + m];
  float sn, cs;
  sincosf(ph, &sn, &cs);
  const c32 alpha = make_float2(rr * cs, rr * sn);
  for (int e = tid; e < 144; e += 64) A[e] = CZERO;
  __syncthreads();
  if (tid < 11) {
    float sq = sqrtf((float)(tid + 1));
    A[(tid + 1) * 12 + tid] = make_float2(alpha.x * sq, alpha.y * sq);
    A[tid * 12 + tid + 1] = make_float2(-alpha.x * sq, alpha.y * sq);
  }
  __syncthreads();
  small_expm(A, S, P, T, red, 12, tid);
  if (tid < 12) c0[(size_t)blockIdx.x * 12 + tid] = S[tid * 12];
}

// ---------------- prep: beamsplitter sector blocks (direction-arranged) ----------------
__global__ __launch_bounds__(64) void prep_bs(const float* __restrict__ th1, const float* __restrict__ ph1,
                                              const float* __restrict__ th2, const float* __restrict__ ph2,
                                              c32* __restrict__ BS) {
  __shared__ c32 A[144], S[144], P[144], T[144];
  __shared__ float red[12];
  const int tid = threadIdx.x;
  const int g = blockIdx.x / 23, N = blockIdx.x % 23;
  const int l = g / 12, rem = g % 12, w = rem / 6, gi = rem % 6;
  const float th = (w ? th2 : th1)[l * 6 + gi];
  const float ph = (w ? ph2 : ph1)[l * 6 + gi];
  const int lo = (N > 11) ? (N - 11) : 0;
  const int sz = (N <= 11) ? (N + 1) : (23 - N);
  float sn, cs;
  sincosf(ph, &sn, &cs);
  for (int e = tid; e < sz * sz; e += 64) A[e] = CZERO;
  __syncthreads();
  if (tid + 1 < sz) {
    int t = tid + 1;
    float s1 = th * sqrtf((float)((lo + t) * (N - lo - t + 1)));
    A[(t - 1) * sz + t] = make_float2(cs * s1, sn * s1);
    A[t * sz + t - 1] = make_float2(-cs * s1, sn * s1);
  }
  __syncthreads();
  small_expm(A, S, P, T, red, sz, tid);
  c32* dst = BS + (size_t)g * 1156 + d_secoff[N];
  const bool upSec = (N <= 11);
  for (int e = tid; e < sz * sz; e += 64) {
    int p = e / sz, q = e - p * sz;
    int qs = upSec ? q : (sz - 1 - q);
    dst[p * sz + q] = S[p * sz + qs];
  }
}

// ---------------- prep: per-mode composites P1 = S*R1, P2 = K*Disp*R2 ----------------
__global__ __launch_bounds__(64) void prep_p(const float* __restrict__ r_, const float* __restrict__ phir,
                                             const float* __restrict__ vphi1,
                                             const float* __restrict__ a_, const float* __restrict__ phia,
                                             const float* __restrict__ vphi2, const float* __restrict__ kk,
                                             c32* __restrict__ P1, c32* __restrict__ P2) {
  __shared__ c32 A[144], S[144], P[144], T[144];
  __shared__ float red[12];
  const int tid = threadIdx.x;
  const int which = blockIdx.x >> 3, lm = blockIdx.x & 7;
  for (int e = tid; e < 144; e += 64) A[e] = CZERO;
  __syncthreads();
  if (which == 0) {
    const float rv = r_[lm], pv = phir[lm];
    float sn, cs;
    sincosf(pv, &sn, &cs);
    const c32 z = make_float2(rv * cs, rv * sn);
    if (tid < 10) {
      float sq = 0.5f * sqrtf((float)((tid + 1) * (tid + 2)));
      A[tid * 12 + tid + 2] = make_float2(z.x * sq, -z.y * sq);
      A[(tid + 2) * 12 + tid] = make_float2(-z.x * sq, -z.y * sq);
    }
  } else {
    const float av = a_[lm], pv = phia[lm];
    float sn, cs;
    sincosf(pv, &sn, &cs);
    const c32 alpha = make_float2(av * cs, av * sn);
    if (tid < 11) {
      float sq = sqrtf((float)(tid + 1));
      A[(tid + 1) * 12 + tid] = make_float2(alpha.x * sq, alpha.y * sq);
      A[tid * 12 + tid + 1] = make_float2(-alpha.x * sq, alpha.y * sq);
    }
  }
  __syncthreads();
  small_expm(A, S, P, T, red, 12, tid);
  if (which == 0) {
    const float vp = vphi1[lm];
    for (int e = tid; e < 144; e += 64) {
      int j = e % 12;
      float sn, cs;
      sincosf(vp * (float)j, &sn, &cs);
      P1[(size_t)lm * 144 + e] = cmul(S[e], make_float2(cs, sn));
    }
  } else {
    const float vp = vphi2[lm], kv = kk[lm];
    for (int e = tid; e < 144; e += 64) {
      int i = e / 12, j = e % 12;
      float sn1, cs1, sn2, cs2;
      sincosf(vp * (float)j, &sn1, &cs1);
      float ang = kv * (float)i;
      ang *= (float)i;
      sincosf(ang, &sn2, &cs2);
      P2[(size_t)lm * 144 + e] = cmul(make_float2(cs2, sn2), cmul(S[e], make_float2(cs1, sn1)));
    }
  }
}

// ---------------- fused pass over modes {1,2,3}: BS(2,3) -> BS(1,2) -> U1 -> U2 -> U3 ----------------
// Slab (b,n0) of 1728 c32; LDS [144 rows][14] (12 used + 2 pad). 144 tasks, 12-spectator batch.
__global__ __launch_bounds__(256) void k123_kernel(
    c32* __restrict__ psi,
    const c32* __restrict__ gbs23, const c32* __restrict__ gbs12,
    const c32* __restrict__ gu1, const c32* __restrict__ gu2, const c32* __restrict__ gu3) {
  __shared__ __align__(16) c32 bufA[2016];
  __shared__ __align__(16) c32 bufB[2016];
  __shared__ c32 gate[1168];
  __shared__ c32 gV1[144], gV2[144], gV3[144];
  const int tid = threadIdx.x;
  if (gu1) for (int e = tid; e < 144; e += 256) gV1[e] = gu1[e];
  if (gu2) for (int e = tid; e < 144; e += 256) gV2[e] = gu2[e];
  if (gu3) for (int e = tid; e < 144; e += 256) gV3[e] = gu3[e];
  for (int e = tid; e < 1156; e += 256) gate[e] = gbs23[e];
  c32* slab = psi + (size_t)blockIdx.x * 1728;
  for (int v = tid; v < 864; v += 256) {
    float4 q = ((const float4*)slab)[v];
    int row = v / 6, k = v - row * 6;
    *((float4*)bufA + 7 * row + k) = q;
  }
  __syncthreads();
  const int r = tid;
  RM m;
  if (r < 144) m = rmeta(r);
  // pass 1: BS(2,3) — pattern (n2,n3) inside each 14-strided 12-row block; spectator n1
  if (r < 144) {
    c32 acc[12];
#pragma unroll
    for (int n = 0; n < 12; ++n) acc[n] = CZERO;
    int a = m.a0;
#pragma unroll
    for (int t = 0; t < 12; ++t) {
      c32 g = gate[m.goff + t];
      if (t >= m.sz) g = CZERO;
#pragma unroll
      for (int n = 0; n < 12; ++n) acc[n] = cfma(g, bufA[SST * n + a], acc[n]);
      a += m.da;
    }
    const int wr = ST * (r / 12) + (r % 12);
#pragma unroll
    for (int n = 0; n < 12; ++n) bufB[SST * n + wr] = acc[n];
  }
  __syncthreads();
  for (int e = tid; e < 1156; e += 256) gate[e] = gbs12[e];
  __syncthreads();
  // pass 2: BS(1,2) — pattern rows (n1,n2), spectator n3 in-row (b128 batched)
  if (r < 144) {
    c32 acc[12];
#pragma unroll
    for (int n = 0; n < 12; ++n) acc[n] = CZERO;
    int rho = m.r0;
#pragma unroll
    for (int t = 0; t < 12; ++t) {
      c32 g = gate[m.goff + t];
      if (t >= m.sz) g = CZERO;
      const float4* ip = (const float4*)bufB + 7 * rho;
      float4 w[6];
#pragma unroll
      for (int q = 0; q < 6; ++q) w[q] = ip[q];
#pragma unroll
      for (int n = 0; n < 12; ++n) acc[n] = cfma(g, get2(w, n), acc[n]);
      rho += m.dr;
    }
    float4* op = (float4*)bufA + 7 * r;
#pragma unroll
    for (int q = 0; q < 6; ++q) op[q] = pack2(acc[2 * q], acc[2 * q + 1]);
  }
  c32* cur = bufA;
  c32* nxt = bufB;
  if (gu1) {  // U1 on n1: lane (i,n2)=r, reads rows 12j+n2, writes row r
    __syncthreads();
    if (r < 144) {
      const int i = r / 12, n2 = r - 12 * (r / 12);
      c32 acc[12];
#pragma unroll
      for (int n = 0; n < 12; ++n) acc[n] = CZERO;
#pragma unroll
      for (int j = 0; j < 12; ++j) {
        c32 g = gV1[i * 12 + j];
        const float4* ip = (const float4*)cur + 7 * (12 * j + n2);
        float4 w[6];
#pragma unroll
        for (int q = 0; q < 6; ++q) w[q] = ip[q];
#pragma unroll
        for (int n = 0; n < 12; ++n) acc[n] = cfma(g, get2(w, n), acc[n]);
      }
      float4* op = (float4*)nxt + 7 * r;
#pragma unroll
      for (int q = 0; q < 6; ++q) op[q] = pack2(acc[2 * q], acc[2 * q + 1]);
    }
    c32* t_ = cur; cur = nxt; nxt = t_;
  }
  if (gu2) {  // U2 on n2: lane (n1,i)=r, reads rows 12n1+j, writes row r
    __syncthreads();
    if (r < 144) {
      const int n1 = r / 12, i = r - 12 * (r / 12);
      c32 acc[12];
#pragma unroll
      for (int n = 0; n < 12; ++n) acc[n] = CZERO;
#pragma unroll
      for (int j = 0; j < 12; ++j) {
        c32 g = gV2[i * 12 + j];
        const float4* ip = (const float4*)cur + 7 * (12 * n1 + j);
        float4 w[6];
#pragma unroll
        for (int q = 0; q < 6; ++q) w[q] = ip[q];
#pragma unroll
        for (int n = 0; n < 12; ++n) acc[n] = cfma(g, get2(w, n), acc[n]);
      }
      float4* op = (float4*)nxt + 7 * r;
#pragma unroll
      for (int q = 0; q < 6; ++q) op[q] = pack2(acc[2 * q], acc[2 * q + 1]);
    }
    c32* t_ = cur; cur = nxt; nxt = t_;
  }
  if (gu3) {  // U3 on n3: lane = row r, in-row transform
    __syncthreads();
    if (r < 144) {
      const float4* ip = (const float4*)cur + 7 * r;
      float4 wv[6];
#pragma unroll
      for (int q = 0; q < 6; ++q) wv[q] = ip[q];
      float4* op = (float4*)nxt + 7 * r;
#pragma unroll
      for (int cpair = 0; cpair < 6; ++cpair) {
        c32 s0 = CZERO, s1 = CZERO;
#pragma unroll
        for (int j = 0; j < 12; ++j) {
          c32 v = get2(wv, j);
          s0 = cfma(gV3[(2 * cpair) * 12 + j], v, s0);
          s1 = cfma(gV3[(2 * cpair + 1) * 12 + j], v, s1);
        }
        op[cpair] = pack2(s0, s1);
      }
    }
    c32* t_ = cur; cur = nxt; nxt = t_;
  }
  __syncthreads();
  for (int v = tid; v < 864; v += 256) {
    int row = v / 6, k = v - row * 6;
    ((float4*)slab)[v] = *((const float4*)cur + 7 * row + k);
  }
}

// ---------------- fused pass over modes {0,1}: [init] -> U0 -> BS(0,1) ----------------
// Tile = 144 (n0,n1)-rows x 16 flat (n2,n3)-cols; LDS stride KP=18; 128B-aligned global chunks.
__global__ __launch_bounds__(256) void k01_kernel(
    c32* __restrict__ psi, const c32* __restrict__ c0,
    const c32* __restrict__ gu0, const c32* __restrict__ gbs) {
  __shared__ __align__(16) c32 bufA[2592];
  __shared__ __align__(16) c32 bufB[2592];
  __shared__ c32 gate[1168];
  __shared__ c32 g0v[144];
  __shared__ c32 cv[4][12];
  const int tid = threadIdx.x;
  const int b = blockIdx.x / 9, t = blockIdx.x % 9;
  if (gu0) for (int e = tid; e < 144; e += 256) g0v[e] = gu0[e];
  if (gbs) for (int e = tid; e < 1156; e += 256) gate[e] = gbs[e];
  c32* gbase = psi + (size_t)b * D4 + t * 16;
  if (c0) {
    if (tid < 48) cv[tid / 12][tid % 12] = c0[(size_t)b * 48 + tid];
    __syncthreads();
    for (int e = tid; e < 2304; e += 256) {
      int row = e >> 4, q = e & 15;
      int cc = 16 * t + q, n2 = cc / 12, n3 = cc - 12 * n2;
      bufA[row * KP + q] =
          cmul(cmul(cv[0][row / 12], cv[1][row % 12]), cmul(cv[2][n2], cv[3][n3]));
    }
  } else {
    for (int e = tid; e < 1152; e += 256) {
      int row = e >> 3, q = e & 7;
      ((float4*)(bufA + row * KP))[q] = ((const float4*)(gbase + (size_t)row * 144))[q];
    }
  }
  __syncthreads();
  const int r = tid;
  c32* cur = bufA;
  c32* nxt = bufB;
  if (gu0) {  // U0 on n0: lane (i,n1)=r, reads rows 12j+n1, writes row r
    if (r < 144) {
      const int i = r / 12, n1 = r - 12 * (r / 12);
      c32 acc[16];
#pragma unroll
      for (int n = 0; n < 16; ++n) acc[n] = CZERO;
#pragma unroll
      for (int j = 0; j < 12; ++j) {
        c32 g = g0v[i * 12 + j];
        const float4* ip = (const float4*)(cur + (12 * j + n1) * KP);
        float4 w[8];
#pragma unroll
        for (int q = 0; q < 8; ++q) w[q] = ip[q];
#pragma unroll
        for (int n = 0; n < 16; ++n) acc[n] = cfma(g, get2(w, n), acc[n]);
      }
      float4* op = (float4*)(nxt + r * KP);
#pragma unroll
      for (int q = 0; q < 8; ++q) op[q] = pack2(acc[2 * q], acc[2 * q + 1]);
    }
    c32* t_ = cur; cur = nxt; nxt = t_;
    __syncthreads();
  }
  if (gbs) {  // BS(0,1): pattern rows (n0,n1)
    if (r < 144) {
      RM m = rmeta(r);
      c32 acc[16];
#pragma unroll
      for (int n = 0; n < 16; ++n) acc[n] = CZERO;
      int rho = m.r0;
#pragma unroll
      for (int tt = 0; tt < 12; ++tt) {
        c32 g = gate[m.goff + tt];
        if (tt >= m.sz) g = CZERO;
        const float4* ip = (const float4*)(cur + rho * KP);
        float4 w[8];
#pragma unroll
        for (int q = 0; q < 8; ++q) w[q] = ip[q];
#pragma unroll
        for (int n = 0; n < 16; ++n) acc[n] = cfma(g, get2(w, n), acc[n]);
        rho += m.dr;
      }
      float4* op = (float4*)(nxt + r * KP);
#pragma unroll
      for (int q = 0; q < 8; ++q) op[q] = pack2(acc[2 * q], acc[2 * q + 1]);
    }
    c32* t_ = cur; cur = nxt; nxt = t_;
    __syncthreads();
  }
  for (int e = tid; e < 1152; e += 256) {
    int row = e >> 3, q = e & 7;
    ((float4*)(gbase + (size_t)row * 144))[q] = ((const float4*)(cur + row * KP))[q];
  }
}

// ---------------- expvals: <X_m> = sum 2*sqrt(n+1)*Re(conj(psi_n) psi_{n+1}) ----------------
__global__ __launch_bounds__(256) void expval_kernel(const c32* __restrict__ psi, float* __restrict__ out) {
  __shared__ float red[1024];
  __shared__ float sq2[12];
  const int tid = threadIdx.x, b = blockIdx.x;
  if (tid < 12) sq2[tid] = 2.f * sqrtf((float)(tid + 1));
  __syncthreads();
  const c32* base = psi + (size_t)b * D4;
  float a0 = 0.f, a1 = 0.f, a2 = 0.f, a3 = 0.f;
  for (int e = tid; e < D4; e += 256) {
    c32 p = base[e];
    int n3 = e % 12, t = e / 12;
    int n2 = t % 12; t /= 12;
    int n1 = t % 12, n0 = t / 12;
    if (n3 < 11) { c32 q = base[e + 1];    a3 = fmaf(sq2[n3], fmaf(p.x, q.x, p.y * q.y), a3); }
    if (n2 < 11) { c32 q = base[e + 12];   a2 = fmaf(sq2[n2], fmaf(p.x, q.x, p.y * q.y), a2); }
    if (n1 < 11) { c32 q = base[e + 144];  a1 = fmaf(sq2[n1], fmaf(p.x, q.x, p.y * q.y), a1); }
    if (n0 < 11) { c32 q = base[e + 1728]; a0 = fmaf(sq2[n0], fmaf(p.x, q.x, p.y * q.y), a0); }
  }
  red[tid * 4 + 0] = a0; red[tid * 4 + 1] = a1; red[tid * 4 + 2] = a2; red[tid * 4 + 3] = a3;
  __syncthreads();
  for (int s = 128; s > 0; s >>= 1) {
    if (tid < s) {
      red[tid * 4 + 0] += red[(tid + s) * 4 + 0];
      red[tid * 4 + 1] += red[(tid + s) * 4 + 1];
      red[tid * 4 + 2] += red[(tid + s) * 4 + 2];
      red[tid * 4 + 3] += red[(tid + s) * 4 + 3];
    }
    __syncthreads();
  }
  if (tid < 4) out[b * 4 + tid] = red[tid];
}

extern "C" void kernel_launch(void* const* d_in, const int* in_sizes, int n_in,
                              void* d_out, int out_size, void* d_ws, size_t ws_size,
                              hipStream_t stream) {
  const float* x      = (const float*)d_in[0];
  const float* theta1 = (const float*)d_in[1];
  const float* phi1   = (const float*)d_in[2];
  const float* vphi1  = (const float*)d_in[3];
  const float* r_     = (const float*)d_in[4];
  const float* phir   = (const float*)d_in[5];
  const float* theta2 = (const float*)d_in[6];
  const float* phi2   = (const float*)d_in[7];
  const float* vphi2  = (const float*)d_in[8];
  const float* a_     = (const float*)d_in[9];
  const float* phia   = (const float*)d_in[10];
  const float* kk     = (const float*)d_in[11];
  float* out = (float*)d_out;

  // workspace layout (bytes)
  const size_t PSI_OFF = 0;                              // 1024*20736*8
  const size_t C0_OFF  = 169869312;                      // 1024*4*12*8
  const size_t P1_OFF  = C0_OFF + 393216;
  const size_t P2_OFF  = P1_OFF + 9216;
  const size_t BS_OFF  = P2_OFF + 9216;                  // 24*1156*8
  const size_t NEED    = BS_OFF + 221952;
  if (ws_size < NEED) return;

  char* ws = (char*)d_ws;
  c32* psi = (c32*)(ws + PSI_OFF);
  c32* c0  = (c32*)(ws + C0_OFF);
  c32* P1  = (c32*)(ws + P1_OFF);
  c32* P2  = (c32*)(ws + P2_OFF);
  c32* BS  = (c32*)(ws + BS_OFF);

  prep_disp<<<dim3(4096), dim3(64), 0, stream>>>(x, c0);
  prep_bs<<<dim3(552), dim3(64), 0, stream>>>(theta1, phi1, theta2, phi2, BS);
  prep_p<<<dim3(16), dim3(64), 0, stream>>>(r_, phir, vphi1, a_, phia, vphi2, kk, P1, P2);

  for (int l = 0; l < 2; ++l) {
    c32* bsl = BS + (size_t)l * 12 * 1156;
    const c32* c0arg = (l == 0) ? c0 : (const c32*)nullptr;
    const c32* u0pre = (l == 0) ? (const c32*)nullptr : (const c32*)(P2 + (size_t)(l - 1) * 4 * 144);
    // interferometer 1: Clements order (0,1),(2,3),(1,2),(0,1),(2,3),(1,2)
    k01_kernel<<<dim3(9216), dim3(256), 0, stream>>>(psi, c0arg, u0pre, bsl + 0 * 1156);
    k123_kernel<<<dim3(12288), dim3(256), 0, stream>>>(psi, bsl + 1 * 1156, bsl + 2 * 1156,
                                                       nullptr, nullptr, nullptr);
    k01_kernel<<<dim3(9216), dim3(256), 0, stream>>>(psi, nullptr, nullptr, bsl + 3 * 1156);
    k123_kernel<<<dim3(12288), dim3(256), 0, stream>>>(psi, bsl + 4 * 1156, bsl + 5 * 1156,
                                                       P1 + (size_t)(l * 4 + 1) * 144,
                                                       P1 + (size_t)(l * 4 + 2) * 144,
                                                       P1 + (size_t)(l * 4 + 3) * 144);
    // interferometer 2 (P1 mode-0 composite rides along before its first BS(0,1))
    k01_kernel<<<dim3(9216), dim3(256), 0, stream>>>(psi, nullptr, P1 + (size_t)(l * 4 + 0) * 144, bsl + 6 * 1156);
    k123_kernel<<<dim3(12288), dim3(256), 0, stream>>>(psi, bsl + 7 * 1156, bsl + 8 * 1156,
                                                       nullptr, nullptr, nullptr);
    k01_kernel<<<dim3(9216), dim3(256), 0, stream>>>(psi, nullptr, nullptr, bsl + 9 * 1156);
    k123_kernel<<<dim3(12288), dim3(256), 0, stream>>>(psi, bsl + 10 * 1156, bsl + 11 * 1156,
                                                       P2 + (size_t)(l * 4 + 1) * 144,
                                                       P2 + (size_t)(l * 4 + 2) * 144,
                                                       P2 + (size_t)(l * 4 + 3) * 144);
  }
  // final pending mode-0 composite from layer 2
  k01_kernel<<<dim3(9216), dim3(256), 0, stream>>>(psi, nullptr, P2 + (size_t)(1 * 4 + 0) * 144, nullptr);
  expval_kernel<<<dim3(1024), dim3(256), 0, stream>>>(psi, out);
}